// Round 6
// baseline (52.272 us; speedup 1.0000x reference)
//
#include <hip/hip_runtime.h>

// FocalLoss, 2 categories, negative handling.
// Identity: bce(-x,1-y) == bce(x,y) => focal_neg == focal elementwise.
// loss[row] = (label!=0) ? sum_c f1*mask : sum_c f0.
//
// Round 5 -> 6: cross-chunk software pipeline. Each wave owns TWO 256-row
// chunks; the 14 (logit,mask) uint4 tiles form one flat stream consumed
// through a 3-slot rolling register buffer (issue tile g+2 while computing
// tile g). Chunk 1's first loads are issued during chunk 0's phases 5-6, so
// they fly during chunk 0's LDS transpose-read + store bubble. VGPR budget:
// 3x(lg+mk) uint4 = 24 + labels 8 + temps ~= 55, under the 64-reg cliff
// (32 waves/CU). LDS layout unchanged from R5 (A[448]+B[192] float2 = 20KB,
// conflict-free). No barriers: wave-private LDS, same-wave DS pipe in-order
// (chunk0 reads issue before chunk1 writes; validated R3-R5).

#define TPB 256

__device__ __forceinline__ void focal_both(float x, float& f0, float& f1) {
    float a  = fabsf(x);
    float e  = __expf(-a);                    // exp(-|x|) in (0,1]
    float r  = __builtin_amdgcn_rcpf(1.0f + e);
    float q  = e * r;                         // r+q == 1
    float Lg = __logf(1.0f + e);              // = -log r ;  -log q = a+Lg
    float tr = q * q * Lg;                    // focal when pt=r
    float tq = r * r * (a + Lg);              // focal when pt=q
    bool xpos = (x >= 0.0f);
    f1 = xpos ? tr : tq;                      // label==1
    f0 = xpos ? tq : tr;                      // label==0
}

// elementwise phase for one (k) tile: partials -> LDS. Uses/updates m, mu.
#define PHASE(lgc, mkc)                                              \
    {                                                                \
        float4 xf = *reinterpret_cast<float4*>(&(lgc));              \
        float    xs[4] = { xf.x, xf.y, xf.z, xf.w };                 \
        unsigned msx[4] = { (mkc).x, (mkc).y, (mkc).z, (mkc).w };    \
        float A0=0.f, A1=0.f, B0=0.f, B1=0.f;                        \
        _Pragma("unroll")                                            \
        for (int j = 0; j < 4; ++j) {                                \
            float f0, f1; focal_both(xs[j], f0, f1);                 \
            float fm = msx[j] ? f1 : 0.0f;                           \
            bool toB = (mu + j) >= 7;                                \
            A0 += toB ? 0.0f : f0;  B0 += toB ? f0 : 0.0f;           \
            A1 += toB ? 0.0f : fm;  B1 += toB ? fm : 0.0f;           \
        }                                                            \
        A[k * 64 + L] = make_float2(A0, A1);                         \
        if (mu >= 4) Bc[3 * m + (mu - 4)] = make_float2(B0, B1);     \
        m += (mu == 3) ? 10 : 9;                                     \
        mu += 4; if (mu >= 7) mu -= 7;                               \
    }

// transpose-combine from LDS + label select + float4 store
#define COMBINE_STORE(lab4, outIdx)                                  \
    {                                                                \
        float2 a0=A[L*7+0], a1=A[L*7+1], a2=A[L*7+2], a3=A[L*7+3],   \
               a4=A[L*7+4], a5=A[L*7+5], a6=A[L*7+6];                \
        float2 b0=Bc[L*3+0], b1=Bc[L*3+1], b2=Bc[L*3+2];             \
        float t00=a0.x+a1.x,      t10=a0.y+a1.y;                     \
        float t01=b0.x+a2.x+a3.x, t11=b0.y+a2.y+a3.y;                \
        float t02=b1.x+a4.x+a5.x, t12=b1.y+a4.y+a5.y;                \
        float t03=b2.x+a6.x,      t13=b2.y+a6.y;                     \
        float4 res;                                                  \
        res.x = ((lab4).x != 0) ? t10 : t00;                         \
        res.y = ((lab4).y != 0) ? t11 : t01;                         \
        res.z = ((lab4).z != 0) ? t12 : t02;                         \
        res.w = ((lab4).w != 0) ? t13 : t03;                         \
        reinterpret_cast<float4*>(out)[(outIdx)] = res;              \
    }

__device__ __forceinline__ void partial_chunk(
    long R0, int B, int L,
    const float* __restrict__ logit, const int* __restrict__ label,
    const int* __restrict__ repr_mask, float* __restrict__ out)
{
    long r4 = R0 / 4 + L;
    long Q  = (long)B >> 2;
    if (r4 < Q && r4 * 4 >= R0 && r4 * 4 < R0 + 256) {
        float res[4];
#pragma unroll
        for (int rr = 0; rr < 4; ++rr) {
            long row = r4 * 4 + rr;
            bool yy = (label[row] != 0);
            float tot = 0.f, ms = 0.f;
            for (int c = 0; c < 7; ++c) {
                float f0, f1;
                focal_both(logit[(size_t)row * 7 + c], f0, f1);
                tot += f0;
                ms  += repr_mask[(size_t)row * 7 + c] ? f1 : 0.f;
            }
            res[rr] = yy ? ms : tot;
        }
        reinterpret_cast<float4*>(out)[r4] =
            make_float4(res[0], res[1], res[2], res[3]);
    }
}

__global__ __launch_bounds__(TPB, 8) void focal_loss_kernel(
    const float* __restrict__ logit,
    const int*   __restrict__ label,
    const int*   __restrict__ repr_mask,
    float*       __restrict__ out,
    int B)
{
    __shared__ float2 sA[4][448];             // 14 KiB: (A0,A1) per u
    __shared__ float2 sB[4][192];             // 6 KiB: (B0,B1), crossing u only

    const int tid = threadIdx.x;
    const int L   = tid & 63;
    const int w   = tid >> 6;
    float2* A  = sA[w];
    float2* Bc = sB[w];

    const long c0 = ((long)blockIdx.x * 4 + w) * 2;   // two chunks per wave
    const long c1 = c0 + 1;
    const long R0 = c0 * 256;
    const long R1 = c1 * 256;

    // m = u/7, mu = (4u)%7 at u = L (k=0); updated incrementally per tile
    const int m_init  = (L * 9363) >> 16;     // L/7
    const int r0i     = L - 7 * m_init;
    const int t4      = 4 * r0i;
    const int mu_init = t4 - 7 * ((t4 * 9363) >> 16);   // (4L)%7

    const bool full0 = (R0 + 256 <= (long)B);
    const bool full1 = (R1 + 256 <= (long)B);

    if (full0) {
        const uint4* lgA = reinterpret_cast<const uint4*>(logit)     + (size_t)c0 * 448;
        const uint4* mkA = reinterpret_cast<const uint4*>(repr_mask) + (size_t)c0 * 448;
        const uint4* lgB = reinterpret_cast<const uint4*>(logit)     + (size_t)c1 * 448;
        const uint4* mkB = reinterpret_cast<const uint4*>(repr_mask) + (size_t)c1 * 448;

        // rolling 3-slot buffers over the flat tile stream g = 0..13
        uint4 plg[3], pmk[3];
        plg[0] = lgA[0 * 64 + L]; pmk[0] = mkA[0 * 64 + L];
        plg[1] = lgA[1 * 64 + L]; pmk[1] = mkA[1 * 64 + L];
        int4 lab0 = reinterpret_cast<const int4*>(label)[c0 * 64 + L];
        int4 lab1 = make_int4(0, 0, 0, 0);

        int m = m_init, mu = mu_init;
        // ---- chunk 0: tiles g = k, consume slot k%3, prefetch slot (k+2)%3 ----
#pragma unroll
        for (int k = 0; k < 7; ++k) {
            if (k + 2 <= 6) {
                plg[(k + 2) % 3] = lgA[(k + 2) * 64 + L];
                pmk[(k + 2) % 3] = mkA[(k + 2) * 64 + L];
            } else if (full1) {               // g = 7,8 -> chunk1 tiles 0,1
                plg[(k + 2) % 3] = lgB[(k - 5) * 64 + L];
                pmk[(k + 2) % 3] = mkB[(k - 5) * 64 + L];
            }
            if (k == 3 && full1)
                lab1 = reinterpret_cast<const int4*>(label)[c1 * 64 + L];

            uint4 lgc = plg[k % 3];
            uint4 mkc = pmk[k % 3];
            PHASE(lgc, mkc);
        }
        COMBINE_STORE(lab0, (size_t)c0 * 64 + L);

        if (full1) {
            // ---- chunk 1: tiles g = 7+k, consume slot (k+1)%3, prefetch k%3 ----
            m = m_init; mu = mu_init;
#pragma unroll
            for (int k = 0; k < 7; ++k) {
                if (k + 2 <= 6) {             // g+2 = 9+k, slot (9+k)%3 = k%3
                    plg[k % 3] = lgB[(k + 2) * 64 + L];
                    pmk[k % 3] = mkB[(k + 2) * 64 + L];
                }
                uint4 lgc = plg[(k + 1) % 3];
                uint4 mkc = pmk[(k + 1) % 3];
                PHASE(lgc, mkc);
            }
            COMBINE_STORE(lab1, (size_t)c1 * 64 + L);
        } else if (R1 < (long)B) {
            partial_chunk(R1, B, L, logit, label, repr_mask, out);
        }
    } else if (R0 < (long)B) {
        partial_chunk(R0, B, L, logit, label, repr_mask, out);
        // full0 false => R0+256 > B => chunk c1 has no rows
    }

    // scalar tail for B % 4 != 0 (not hit for B = 4M)
    if ((B & 3) && blockIdx.x == 0 && tid == 0) {
        for (long row = (long)(B >> 2) * 4; row < B; ++row) {
            bool yy = (label[row] != 0);
            float tot = 0.f, ms = 0.f;
            for (int c = 0; c < 7; ++c) {
                float f0, f1;
                focal_both(logit[(size_t)row * 7 + c], f0, f1);
                tot += f0;
                ms  += repr_mask[(size_t)row * 7 + c] ? f1 : 0.f;
            }
            out[row] = yy ? ms : tot;
        }
    }
}

extern "C" void kernel_launch(void* const* d_in, const int* in_sizes, int n_in,
                              void* d_out, int out_size, void* d_ws, size_t ws_size,
                              hipStream_t stream) {
    const float* logit     = (const float*)d_in[0];
    const int*   label     = (const int*)d_in[1];
    const int*   repr_mask = (const int*)d_in[2];
    float*       out       = (float*)d_out;

    int B = in_sizes[1];                      // label has B elements
    long chunks = ((long)B + 255) / 256;      // 256-row chunks
    long slots  = (chunks + 1) / 2;           // 2 chunks per wave
    int blocks  = (int)((slots + 3) / 4);     // 4 waves per block
    if (blocks < 1) blocks = 1;

    focal_loss_kernel<<<blocks, TPB, 0, stream>>>(logit, label, repr_mask, out, B);
}

// Round 8
// 43.219 us; speedup vs baseline: 1.2095x; 1.2095x over previous
//
#include <hip/hip_runtime.h>

// FocalLoss, 2 categories, negative handling.
// Identity: bce(-x,1-y) == bce(x,y) => focal_neg == focal elementwise.
// loss[row] = (label!=0) ? sum_c f1*mask : sum_c f0.
//
// Round 7 -> 8: same as R7 (R5 structure + nontemporal output store), with
// the compile fix: __builtin_nontemporal_store needs a NATIVE vector type,
// not HIP's float4 class. Use ext_vector_type(4) alias for the store.
//
// R5 structure recap: one 256-row chunk per wave; float2 A[448] + compact
// float2 B[192] partial-sum staging (20 KiB/block, conflict-free, 8 blk/CU);
// depth-2 register pipeline on loads; one-log focal math; no barriers
// (wave-private LDS, same-wave DS pipe in-order).

#define TPB 256

typedef float f32x4 __attribute__((ext_vector_type(4)));

__device__ __forceinline__ void focal_both(float x, float& f0, float& f1) {
    float a  = fabsf(x);
    float e  = __expf(-a);                    // exp(-|x|) in (0,1]
    float r  = __builtin_amdgcn_rcpf(1.0f + e);
    float q  = e * r;                         // r+q == 1
    float Lg = __logf(1.0f + e);              // = -log r ;  -log q = a+Lg
    float tr = q * q * Lg;                    // focal when pt=r
    float tq = r * r * (a + Lg);              // focal when pt=q
    bool xpos = (x >= 0.0f);
    f1 = xpos ? tr : tq;                      // label==1
    f0 = xpos ? tq : tr;                      // label==0
}

__global__ __launch_bounds__(TPB, 8) void focal_loss_kernel(
    const float* __restrict__ logit,
    const int*   __restrict__ label,
    const int*   __restrict__ repr_mask,
    float*       __restrict__ out,
    int B)
{
    __shared__ float2 sA[4][448];             // 14 KiB: (A0,A1) for every u
    __shared__ float2 sB[4][192];             // 6 KiB: (B0,B1) for crossing u

    const int tid = threadIdx.x;
    const int L   = tid & 63;
    const int w   = tid >> 6;
    const int wc  = blockIdx.x * 4 + w;       // wave chunk: 256 rows
    const long R0 = (long)wc * 256;

    float2* A  = sA[w];
    float2* Bc = sB[w];

    if (R0 + 256 <= B) {
        // ---- fast path: full 256-row chunk = 448 uint4 of logit/mask ----
        const uint4* lg4 = reinterpret_cast<const uint4*>(logit)     + (size_t)wc * 448;
        const uint4* mk4 = reinterpret_cast<const uint4*>(repr_mask) + (size_t)wc * 448;
        int4 lab4 = reinterpret_cast<const int4*>(label)[(size_t)wc * 64 + L];

        // u = k*64 + L ; m = u/7, mu = (4u)%7, tracked incrementally.
        int m  = (L * 9363) >> 16;            // L/7 (exact for L < 448)
        int r0 = L - 7 * m;                   // L%7
        int t4 = 4 * r0;
        int mu = t4 - 7 * ((t4 * 9363) >> 16);// (4L)%7

        uint4 lgc = lg4[L];
        uint4 mkc = mk4[L];
#pragma unroll
        for (int k = 0; k < 7; ++k) {
            uint4 lgn, mkn;
            if (k < 6) {                      // depth-2 pipeline: next tile
                lgn = lg4[(k + 1) * 64 + L];
                mkn = mk4[(k + 1) * 64 + L];
            }
            float4 xf = *reinterpret_cast<float4*>(&lgc);
            float    xs[4] = { xf.x, xf.y, xf.z, xf.w };
            unsigned ms[4] = { mkc.x, mkc.y, mkc.z, mkc.w };

            float A0 = 0.f, A1 = 0.f, B0 = 0.f, B1 = 0.f;
#pragma unroll
            for (int j = 0; j < 4; ++j) {
                float f0, f1;
                focal_both(xs[j], f0, f1);
                float fm = ms[j] ? f1 : 0.0f;
                bool toB = (mu + j) >= 7;     // element spills into row A+1
                A0 += toB ? 0.0f : f0;
                B0 += toB ? f0   : 0.0f;
                A1 += toB ? 0.0f : fm;
                B1 += toB ? fm   : 0.0f;
            }
            A[k * 64 + L] = make_float2(A0, A1);
            if (mu >= 4)                      // crossing u only
                Bc[3 * m + (mu - 4)] = make_float2(B0, B1);

            // u += 64: mu += 4 (mod 7); m += 9 (+1 more when r wraps, r==6 <=> mu==3)
            m += (mu == 3) ? 10 : 9;
            mu += 4; if (mu >= 7) mu -= 7;
            lgc = lgn; mkc = mkn;
        }

        // transpose-combine: reader L consumes A[7L..7L+6], B[3L..3L+2]
        float2 a0 = A[L * 7 + 0];
        float2 a1 = A[L * 7 + 1];
        float2 a2 = A[L * 7 + 2];
        float2 a3 = A[L * 7 + 3];
        float2 a4 = A[L * 7 + 4];
        float2 a5 = A[L * 7 + 5];
        float2 a6 = A[L * 7 + 6];
        float2 b0 = Bc[L * 3 + 0];            // B of u=7L+1
        float2 b1 = Bc[L * 3 + 1];            // B of u=7L+3
        float2 b2 = Bc[L * 3 + 2];            // B of u=7L+5

        float t0_0 = a0.x + a1.x;             float t1_0 = a0.y + a1.y;
        float t0_1 = b0.x + a2.x + a3.x;      float t1_1 = b0.y + a2.y + a3.y;
        float t0_2 = b1.x + a4.x + a5.x;      float t1_2 = b1.y + a4.y + a5.y;
        float t0_3 = b2.x + a6.x;             float t1_3 = b2.y + a6.y;

        f32x4 res;
        res.x = (lab4.x != 0) ? t1_0 : t0_0;
        res.y = (lab4.y != 0) ? t1_1 : t0_1;
        res.z = (lab4.z != 0) ? t1_2 : t0_2;
        res.w = (lab4.w != 0) ? t1_3 : t0_3;
        // nontemporal: don't allocate output lines in L2/L3 (keep inputs resident)
        __builtin_nontemporal_store(res,
            reinterpret_cast<f32x4*>(out) + ((size_t)wc * 64 + L));
    } else if (R0 < B) {
        // ---- partial chunk (B % 256): per-lane scalar quad-rows ----
        long r4 = R0 / 4 + L;
        long Q  = B >> 2;
        if (r4 < Q) {
            float res[4];
#pragma unroll
            for (int rr = 0; rr < 4; ++rr) {
                long row = r4 * 4 + rr;
                bool yy = (label[row] != 0);
                float tot = 0.f, ms = 0.f;
                for (int c = 0; c < 7; ++c) {
                    float f0, f1;
                    focal_both(logit[(size_t)row * 7 + c], f0, f1);
                    tot += f0;
                    ms  += repr_mask[(size_t)row * 7 + c] ? f1 : 0.f;
                }
                res[rr] = yy ? ms : tot;
            }
            reinterpret_cast<float4*>(out)[r4] =
                make_float4(res[0], res[1], res[2], res[3]);
        }
    }

    // scalar tail for B % 4 != 0 (not hit for B = 4M)
    if ((B & 3) && blockIdx.x == 0 && tid == 0) {
        for (long row = (long)(B >> 2) * 4; row < B; ++row) {
            bool yy = (label[row] != 0);
            float tot = 0.f, ms = 0.f;
            for (int c = 0; c < 7; ++c) {
                float f0, f1;
                focal_both(logit[(size_t)row * 7 + c], f0, f1);
                tot += f0;
                ms  += repr_mask[(size_t)row * 7 + c] ? f1 : 0.f;
            }
            out[row] = yy ? ms : tot;
        }
    }
}

extern "C" void kernel_launch(void* const* d_in, const int* in_sizes, int n_in,
                              void* d_out, int out_size, void* d_ws, size_t ws_size,
                              hipStream_t stream) {
    const float* logit     = (const float*)d_in[0];
    const int*   label     = (const int*)d_in[1];
    const int*   repr_mask = (const int*)d_in[2];
    float*       out       = (float*)d_out;

    int B = in_sizes[1];                      // label has B elements
    long chunks = ((long)B + 255) / 256;      // 256-row wave chunks
    int blocks = (int)((chunks + 3) / 4);
    if (blocks < 1) blocks = 1;

    focal_loss_kernel<<<blocks, TPB, 0, stream>>>(logit, label, repr_mask, out, B);
}